// Round 10
// baseline (426.357 us; speedup 1.0000x reference)
//
#include <hip/hip_runtime.h>

typedef unsigned short u16;
typedef __attribute__((ext_vector_type(4))) float f32x4;
typedef __attribute__((ext_vector_type(16))) float f32x16;
typedef __attribute__((ext_vector_type(8))) short s16x8;
typedef __attribute__((ext_vector_type(2))) unsigned int u32x2v;

#define CEXP 0.12751742929f  // log2(e)/sqrt(128)

static __device__ __forceinline__ u16 f2bf(float x) {
  unsigned u = __float_as_uint(x);
  u = u + 0x7fffu + ((u >> 16) & 1u);
  return (u16)(u >> 16);
}
static __device__ __forceinline__ unsigned cvtpk(float a, float b) {
  unsigned r;
  asm("v_cvt_pk_bf16_f32 %0, %1, %2" : "=v"(r) : "v"(a), "v"(b));
  return r;
}
static __device__ __forceinline__ u32x2v pswap(unsigned a, unsigned b) {
  return __builtin_amdgcn_permlane32_swap(a, b, false, false);
}
static __device__ __forceinline__ f32x4 fzero() { f32x4 z; z[0]=0.f; z[1]=0.f; z[2]=0.f; z[3]=0.f; return z; }
static __device__ __forceinline__ f32x4 mfma16(s16x8 a, s16x8 b, f32x4 c) {
  return __builtin_amdgcn_mfma_f32_16x16x32_bf16(a, b, c, 0, 0, 0);
}
static __device__ __forceinline__ f32x16 mfma32(s16x8 a, s16x8 b, f32x16 c) {
  return __builtin_amdgcn_mfma_f32_32x32x16_bf16(a, b, c, 0, 0, 0);
}
static __device__ __forceinline__ void gld16(const void* g, void* l) {
  __builtin_amdgcn_global_load_lds((const __attribute__((address_space(1))) void*)g,
                                   (__attribute__((address_space(3))) void*)l, 16, 0, 0);
}

// ---------------- fused fp32 -> bf16 conversions (x, 4 weights, past_k) ----------------
__global__ void cvt_all(const float* __restrict__ x, const float* __restrict__ wq,
                        const float* __restrict__ wk, const float* __restrict__ wv,
                        const float* __restrict__ wo, const float* __restrict__ pk,
                        u16* __restrict__ xb, u16* __restrict__ wqb, u16* __restrict__ wkb,
                        u16* __restrict__ wvb, u16* __restrict__ wob, u16* __restrict__ kc) {
  int stride = gridDim.x * blockDim.x;
  for (int i4 = blockIdx.x * blockDim.x + threadIdx.x; i4 < 8388608; i4 += stride) {
    const float* s; u16* d; int i; size_t di;
    if (i4 < 2097152)      { i = i4 * 4;             s = x;  d = xb;  di = i; }
    else if (i4 < 3145728) { i = (i4 - 2097152) * 4; s = wq; d = wqb; di = i; }
    else if (i4 < 4194304) { i = (i4 - 3145728) * 4; s = wk; d = wkb; di = i; }
    else if (i4 < 5242880) { i = (i4 - 4194304) * 4; s = wv; d = wvb; di = i; }
    else if (i4 < 6291456) { i = (i4 - 5242880) * 4; s = wo; d = wob; di = i; }
    else { i = (i4 - 6291456) * 4; s = pk; d = kc; di = (size_t)i + ((size_t)(i >> 18) << 18); }
    float4 v = *reinterpret_cast<const float4*>(s + i);
    ushort4 o;
    o.x = f2bf(v.x); o.y = f2bf(v.y); o.z = f2bf(v.z); o.w = f2bf(v.w);
    *reinterpret_cast<ushort4*>(d + di) = o;
  }
}

// ---------------- V transpose: [bh][2048][128] -> Vt [bh][128][4096] (row-major) ----------------
__global__ void transpose_past_v(const float* __restrict__ src, u16* __restrict__ dst) {
  __shared__ u16 tile[64 * 138];
  int bh = blockIdx.y, pt = blockIdx.x;
  const float* s = src + ((size_t)bh * 2048 + (size_t)pt * 64) * 128;
  int t = threadIdx.x;
#pragma unroll
  for (int it = 0; it < 8; ++it) {
    int idx = it * 1024 + t * 4;
    int row = idx >> 7, col = idx & 127;
    float4 v = *reinterpret_cast<const float4*>(s + idx);
    u16* d = &tile[row * 138 + col];
    d[0] = f2bf(v.x); d[1] = f2bf(v.y); d[2] = f2bf(v.z); d[3] = f2bf(v.w);
  }
  __syncthreads();
  size_t dbase = (size_t)bh * 128 * 4096 + (size_t)pt * 64;
#pragma unroll
  for (int it = 0; it < 32; ++it) {
    int o = it * 256 + t;
    int dd = o >> 6, pos = o & 63;
    dst[dbase + (size_t)dd * 4096 + pos] = tile[pos * 138 + dd];
  }
}

__global__ void transpose_new_v(const u16* __restrict__ src, u16* __restrict__ dst) {
  __shared__ u16 tile[64 * 138];
  int bh = blockIdx.y, pt = blockIdx.x;
  const u16* s = src + ((size_t)bh * 2048 + (size_t)pt * 64) * 128;
  int t = threadIdx.x;
#pragma unroll
  for (int it = 0; it < 8; ++it) {
    int idx = it * 1024 + t * 4;
    int row = idx >> 7, col = idx & 127;
    ushort4 v = *reinterpret_cast<const ushort4*>(s + idx);
    u16* d = &tile[row * 138 + col];
    d[0] = v.x; d[1] = v.y; d[2] = v.z; d[3] = v.w;
  }
  __syncthreads();
  size_t dbase = (size_t)bh * 128 * 4096 + 2048 + (size_t)pt * 64;
#pragma unroll
  for (int it = 0; it < 32; ++it) {
    int o = it * 256 + t;
    int dd = o >> 6, pos = o & 63;
    dst[dbase + (size_t)dd * 4096 + pos] = tile[pos * 138 + dd];
  }
}

// ---------------- 128x128 GEMM core, counted-vmcnt pipeline (proj) ----------------
static __device__ __forceinline__ void gemm_core(const u16* __restrict__ A, const u16* __restrict__ Wn,
                                                 int m0, char* ldsb, f32x4 (&acc)[4][4]) {
  const int tid = threadIdx.x;
  const int w = tid >> 6, lane = tid & 63, g = lane >> 4, ln = lane & 15;
#pragma unroll
  for (int mi = 0; mi < 4; ++mi)
#pragma unroll
    for (int ni = 0; ni < 4; ++ni) acc[mi][ni] = fzero();

  auto stage = [&](int buf, int k0) {
#pragma unroll
    for (int i = 0; i < 2; ++i) {
      int c = w * 2 + i;
      int p = c * 1024 + lane * 16;
      int row = p >> 6;
      int colb = (p & 63) ^ ((row & 3) << 4);
      const u16* sa = A + (size_t)(m0 + row) * 2048 + k0 + (colb >> 1);
      const u16* sw = Wn + (size_t)row * 2048 + k0 + (colb >> 1);
      char* da = ldsb + buf * 16384 + c * 1024;
      gld16(sa, da);
      gld16(sw, da + 8192);
    }
  };
  stage(0, 0);
  const int wr = w >> 1, wc = w & 1;
  for (int kt = 0; kt < 64; ++kt) {
    int cur = kt & 1;
    if (kt < 63) {
      stage(cur ^ 1, (kt + 1) * 32);
      asm volatile("s_waitcnt vmcnt(4)\n\ts_barrier" ::: "memory");
    } else {
      asm volatile("s_waitcnt vmcnt(0)\n\ts_barrier" ::: "memory");
    }
    const char* bp = ldsb + cur * 16384;
    s16x8 af[4], bw[4];
#pragma unroll
    for (int mi = 0; mi < 4; ++mi) {
      int row = wr * 64 + mi * 16 + ln;
      int lin = row * 64 + g * 16;
      af[mi] = *reinterpret_cast<const s16x8*>(bp + (lin ^ ((row & 3) << 4)));
    }
#pragma unroll
    for (int ni = 0; ni < 4; ++ni) {
      int row = wc * 64 + ni * 16 + ln;
      int lin = row * 64 + g * 16;
      bw[ni] = *reinterpret_cast<const s16x8*>(bp + 8192 + (lin ^ ((row & 3) << 4)));
    }
#pragma unroll
    for (int mi = 0; mi < 4; ++mi)
#pragma unroll
      for (int ni = 0; ni < 4; ++ni)
        acc[mi][ni] = mfma16(af[mi], bw[ni], acc[mi][ni]);
    asm volatile("s_waitcnt lgkmcnt(0)\n\ts_barrier" ::: "memory");
  }
}

// ---------------- fused QKV projection: 128x256 tile, 8 waves, 2-K-tile deep pipeline ----------------
// grid 768 (=3 exact CU rounds), XCD-swizzled. Frag-major LDS (0 conflicts).
// Iter t: [vmcnt(0)+bar; issue buf1<-2t+1; 4 quadrant phases on buf0; vmcnt(0)+bar;
//          issue buf0<-2t+2; 4 phases on buf1]. Every load has a half-iter of cover.
__global__ __launch_bounds__(512, 1) void qkv_gemm8(const u16* __restrict__ xb,
    const u16* __restrict__ wq, const u16* __restrict__ wk, const u16* __restrict__ wv,
    const float* __restrict__ bq, const float* __restrict__ bk, const float* __restrict__ bv,
    u16* __restrict__ outq, u16* __restrict__ kc, u16* __restrict__ outv) {
  __shared__ char lds[98304];  // 2 bufs x (A 16KB + B 32KB)
  const int tid = threadIdx.x;
  const int w = tid >> 6, lane = tid & 63, g = lane >> 4, ln = lane & 15;
  const int wr = w >> 2, wc = w & 3;          // 2M x 4N waves, 64x64 per wave
  const int bid = blockIdx.x;
  const int swz = (bid & 7) * 96 + (bid >> 3);  // bijective XCD swizzle (768 % 8 == 0)
  const int mx = swz & 31, nb = swz >> 5;       // 32 m-blocks x 24 n-blocks
  const int m0 = mx * 128;
  const int wsel = nb >> 3;
  const int n0w = (nb & 7) * 256;               // column offset within selected weight
  const u16* W; const float* bias; u16* dst; int lrow, off;
  if (wsel == 0)      { W = wq; bias = bq; dst = outq; lrow = 2048; off = 0; }
  else if (wsel == 1) { W = wk; bias = bk; dst = kc;   lrow = 4096; off = 2048; }
  else                { W = wv; bias = bv; dst = outv; lrow = 2048; off = 0; }

  f32x4 acc[4][4];
#pragma unroll
  for (int mi = 0; mi < 4; ++mi)
#pragma unroll
    for (int ni = 0; ni < 4; ++ni) acc[mi][ni] = fzero();

  // stage one K-tile (48 chunks of 1KB: A chunks 0-15, B chunks 16-47); 6 chunks/wave
  auto issue6 = [&](int bufoff, int kt) {
    int k0 = kt * 64;
#pragma unroll
    for (int s = 0; s < 6; ++s) {
      int c = w * 6 + s;
      if (c < 16) {
        int mi_g = c >> 1, ks = c & 1;   // A frag: lane holds A[m0+mi_g*16+ln][k0+ks*32+g*8..+7]
        gld16(xb + (size_t)(m0 + mi_g * 16 + ln) * 2048 + k0 + ks * 32 + g * 8,
              lds + bufoff + c * 1024);
      } else {
        int cb = c - 16;
        int ni_g = cb >> 1, ks = cb & 1; // B frag: lane holds W[n0w+ni_g*16+ln][k0+ks*32+g*8..+7]
        gld16(W + (size_t)(n0w + ni_g * 16 + ln) * 2048 + k0 + ks * 32 + g * 8,
              lds + bufoff + 16384 + cb * 1024);
      }
    }
  };
  // one K-tile of compute: 4 quadrant phases, 8 ds_read + 8 MFMA each
  auto half = [&](int bufoff) {
#pragma unroll
    for (int q = 0; q < 4; ++q) {
      int mh = q >> 1, nh = q & 1;
      s16x8 af[2][2], bw2[2][2];
#pragma unroll
      for (int i = 0; i < 2; ++i)
#pragma unroll
        for (int ks = 0; ks < 2; ++ks) {
          af[i][ks]  = *reinterpret_cast<const s16x8*>(
              lds + bufoff + (((wr * 4 + mh * 2 + i) << 1) + ks) * 1024 + lane * 16);
          bw2[i][ks] = *reinterpret_cast<const s16x8*>(
              lds + bufoff + 16384 + (((wc * 4 + nh * 2 + i) << 1) + ks) * 1024 + lane * 16);
        }
#pragma unroll
      for (int i = 0; i < 2; ++i)
#pragma unroll
        for (int j = 0; j < 2; ++j) {
          acc[mh * 2 + i][nh * 2 + j] = mfma16(af[i][0], bw2[j][0], acc[mh * 2 + i][nh * 2 + j]);
          acc[mh * 2 + i][nh * 2 + j] = mfma16(af[i][1], bw2[j][1], acc[mh * 2 + i][nh * 2 + j]);
        }
    }
  };

  issue6(0, 0);                       // prologue: K-tile 0 (one-time uncovered)
  for (int t = 0; t < 16; ++t) {
    asm volatile("s_waitcnt vmcnt(0)\n\ts_barrier" ::: "memory");  // buf0(2t) landed; buf1 reads sealed
    issue6(49152, 2 * t + 1);         // buf1 <- 2t+1 (covered by half(buf0))
    half(0);
    asm volatile("s_waitcnt vmcnt(0)\n\ts_barrier" ::: "memory");  // buf1(2t+1) landed; buf0 reads sealed
    if (t < 15) issue6(0, 2 * t + 2); // buf0 <- 2t+2 (covered by half(buf1))
    half(49152);
  }

  // epilogue: bias + scatter to head layout (Q/V) or K-cache rows
#pragma unroll
  for (int ni = 0; ni < 4; ++ni) {
    int ncol = n0w + wc * 64 + ni * 16 + ln;
    float bcol = bias[ncol];
    int h = ncol >> 7, hd = ncol & 127;
#pragma unroll
    for (int mi = 0; mi < 4; ++mi) {
#pragma unroll
      for (int r = 0; r < 4; ++r) {
        int rowg = m0 + wr * 64 + mi * 16 + g * 4 + r;
        int b = rowg >> 11, s = rowg & 2047;
        float val = acc[mi][ni][r] + bcol;
        dst[((size_t)(b * 16 + h) * lrow + off + s) * 128 + hd] = f2bf(val);
      }
    }
  }
}

// ---------------- output projection ----------------
__global__ __launch_bounds__(256, 3) void proj_gemm(const u16* __restrict__ ao, const u16* __restrict__ wo,
    const float* __restrict__ bo, float* __restrict__ out) {
  __shared__ char ldsb[32768];
  int m0 = blockIdx.x * 128, n0 = blockIdx.y * 128;
  f32x4 acc[4][4];
  gemm_core(ao, wo + (size_t)n0 * 2048, m0, ldsb, acc);
  const int tid = threadIdx.x, w = tid >> 6, lane = tid & 63, g = lane >> 4, ln = lane & 15;
  const int wr = w >> 1, wc = w & 1;
#pragma unroll
  for (int ni = 0; ni < 4; ++ni) {
    int j = n0 + wc * 64 + ni * 16 + ln;
    float bcol = bo[j];
#pragma unroll
    for (int mi = 0; mi < 4; ++mi) {
#pragma unroll
      for (int r = 0; r < 4; ++r) {
        int rowg = m0 + wr * 64 + mi * 16 + g * 4 + r;
        out[(size_t)rowg * 2048 + j] = acc[mi][ni][r] + bcol;
      }
    }
  }
}

// ---------------- flash attention (R6 best config: 32x32 MFMA, K+V LDS dbuf, vmcnt(8)) ----------------
__global__ __launch_bounds__(256, 2) void attn_kernel(const u16* __restrict__ Qb,
    const u16* __restrict__ Kc, const u16* __restrict__ Vt, u16* __restrict__ Ao) {
  __shared__ char lds[65536];  // 2 bufs x (K 16KB + Vt 16KB)
  const int tid = threadIdx.x, w = tid >> 6, lane = tid & 63;
  const int hi = lane >> 5, l5 = lane & 31;
  const int bh = blockIdx.x;
  const int qy = blockIdx.y;
  const int qbk = (qy & 8) ? (15 - (qy & 7)) : qy;   // complementary pairing
  const int b = bh >> 4, h = bh & 15;
  const u16* Qbh = Qb + (size_t)bh * 2048 * 128;
  const u16* Kbh = Kc + (size_t)bh * 4096 * 128;
  const u16* Vbh = Vt + (size_t)bh * 128 * 4096;

  const int qrow0 = qbk * 128 + w * 32;
  const int qp = 2048 + qrow0 + l5;
  const int qpmin = 2048 + qrow0;
  const int ntiles = (2048 + qbk * 128 + 128) >> 6;

  s16x8 qf[8];
#pragma unroll
  for (int kc = 0; kc < 8; ++kc)
    qf[kc] = *reinterpret_cast<const s16x8*>(Qbh + (size_t)(qrow0 + l5) * 128 + kc * 16 + hi * 8);

  f32x16 o[4];
#pragma unroll
  for (int dt = 0; dt < 4; ++dt)
#pragma unroll
    for (int i = 0; i < 16; ++i) o[dt][i] = 0.f;
  float mrun = -3e38f, lrun = 0.f;

  auto stage = [&](int buf, int kv0) {
    char* base = lds + buf * 32768;
#pragma unroll
    for (int i = 0; i < 4; ++i) {
      int p = (w * 4 + i) * 1024 + lane * 16;
      int row = p >> 8;
      int colb = (p & 255) ^ ((row & 7) << 4);
      gld16(Kbh + (size_t)(kv0 + row) * 128 + (colb >> 1), base + (w * 4 + i) * 1024);
      int vrow = p >> 7;
      int vcol = (p & 127) ^ ((vrow & 7) << 4);
      gld16(Vbh + (size_t)vrow * 4096 + kv0 + (vcol >> 1), base + 16384 + (w * 4 + i) * 1024);
    }
  };

  stage(0, 0);
  for (int t = 0; t < ntiles; ++t) {
    const int kv0 = t * 64;
    const int cur = t & 1;
    if (t + 1 < ntiles) {
      stage(cur ^ 1, kv0 + 64);
      asm volatile("s_waitcnt vmcnt(8)\n\ts_barrier" ::: "memory");
    } else {
      asm volatile("s_waitcnt vmcnt(0)\n\ts_barrier" ::: "memory");
    }
    const char* Kl = lds + cur * 32768;
    const char* Vl = Kl + 16384;
    if (kv0 <= qpmin + 31) {
      f32x16 s0, s1;
#pragma unroll
      for (int i = 0; i < 16; ++i) { s0[i] = 0.f; s1[i] = 0.f; }
      __builtin_amdgcn_s_setprio(1);
#pragma unroll
      for (int kc = 0; kc < 8; ++kc) {
        {
          int row = l5;
          int lin = row * 256 + kc * 32 + hi * 16;
          s16x8 a = *reinterpret_cast<const s16x8*>(Kl + (lin ^ ((row & 7) << 4)));
          s0 = mfma32(a, qf[kc], s0);
        }
        {
          int row = 32 + l5;
          int lin = row * 256 + kc * 32 + hi * 16;
          s16x8 a = *reinterpret_cast<const s16x8*>(Kl + (lin ^ ((row & 7) << 4)));
          s1 = mfma32(a, qf[kc], s1);
        }
      }
      __builtin_amdgcn_s_setprio(0);
      if (kv0 + 63 > qpmin) {
#pragma unroll
        for (int i = 0; i < 16; ++i) {
          int r0 = (i & 3) + 8 * (i >> 2) + 4 * hi;
          if (kv0 + r0 > qp) s0[i] = -3e38f;
          if (kv0 + 32 + r0 > qp) s1[i] = -3e38f;
        }
      }
      float pm = fmaxf(s0[0], s0[1]);
#pragma unroll
      for (int i = 2; i < 16; i += 2) pm = fmaxf(fmaxf(pm, s0[i]), s0[i + 1]);
#pragma unroll
      for (int i = 0; i < 16; i += 2) pm = fmaxf(fmaxf(pm, s1[i]), s1[i + 1]);
      {
        u32x2v rr = pswap(__float_as_uint(pm), __float_as_uint(pm));
        pm = fmaxf(pm, __uint_as_float(hi ? rr[0] : rr[1]));
      }
      float mnew = (pm > mrun + 8.f) ? pm : mrun;
      float fsc = exp2f((mrun - mnew) * CEXP);
      mrun = mnew;
      float r0 = 0.f, r1 = 0.f, r2 = 0.f, r3 = 0.f;
#pragma unroll
      for (int i = 0; i < 16; i += 4) {
        float p0 = exp2f((s0[i] - mnew) * CEXP);
        float p1 = exp2f((s0[i + 1] - mnew) * CEXP);
        float p2 = exp2f((s0[i + 2] - mnew) * CEXP);
        float p3 = exp2f((s0[i + 3] - mnew) * CEXP);
        s0[i] = p0; s0[i + 1] = p1; s0[i + 2] = p2; s0[i + 3] = p3;
        r0 += p0; r1 += p1; r2 += p2; r3 += p3;
      }
#pragma unroll
      for (int i = 0; i < 16; i += 4) {
        float p0 = exp2f((s1[i] - mnew) * CEXP);
        float p1 = exp2f((s1[i + 1] - mnew) * CEXP);
        float p2 = exp2f((s1[i + 2] - mnew) * CEXP);
        float p3 = exp2f((s1[i + 3] - mnew) * CEXP);
        s1[i] = p0; s1[i + 1] = p1; s1[i + 2] = p2; s1[i + 3] = p3;
        r0 += p0; r1 += p1; r2 += p2; r3 += p3;
      }
      float rs = (r0 + r1) + (r2 + r3);
      {
        u32x2v rr = pswap(__float_as_uint(rs), __float_as_uint(rs));
        rs += __uint_as_float(hi ? rr[0] : rr[1]);
      }
      lrun = lrun * fsc + rs;
      if (!__all(fsc == 1.f)) {
#pragma unroll
        for (int dt = 0; dt < 4; ++dt)
#pragma unroll
          for (int i = 0; i < 16; ++i) o[dt][i] *= fsc;
      }
      s16x8 pb[4];
#pragma unroll
      for (int c2 = 0; c2 < 4; ++c2) {
        const f32x16& sv = (c2 & 2) ? s1 : s0;
        const int b0 = (c2 & 1) * 8;
        unsigned x0 = cvtpk(sv[b0 + 0], sv[b0 + 1]);
        unsigned x1 = cvtpk(sv[b0 + 2], sv[b0 + 3]);
        unsigned y0 = cvtpk(sv[b0 + 4], sv[b0 + 5]);
        unsigned y1 = cvtpk(sv[b0 + 6], sv[b0 + 7]);
        u32x2v q0 = pswap(x0, y0);
        u32x2v q1 = pswap(x1, y1);
        union { unsigned u[4]; s16x8 v; } pu;
        pu.u[0] = q0[0]; pu.u[1] = q1[0]; pu.u[2] = q0[1]; pu.u[3] = q1[1];
        pb[c2] = pu.v;
      }
      __builtin_amdgcn_s_setprio(1);
#pragma unroll
      for (int dt = 0; dt < 4; ++dt) {
#pragma unroll
        for (int c2 = 0; c2 < 4; ++c2) {
          int row = dt * 32 + l5;
          int lin = row * 128 + c2 * 32 + hi * 16;
          s16x8 va = *reinterpret_cast<const s16x8*>(Vl + (lin ^ ((row & 7) << 4)));
          o[dt] = mfma32(va, pb[c2], o[dt]);
        }
      }
      __builtin_amdgcn_s_setprio(0);
    }
    asm volatile("s_waitcnt lgkmcnt(0)\n\ts_barrier" ::: "memory");
  }

  float li = 1.f / lrun;
#pragma unroll
  for (int dt = 0; dt < 4; ++dt)
#pragma unroll
    for (int i = 0; i < 16; ++i) o[dt][i] *= li;
  const int qb = w * 32 + l5;
#pragma unroll
  for (int dt = 0; dt < 4; ++dt) {
#pragma unroll
    for (int rg = 0; rg < 4; ++rg) {
      int d0 = dt * 32 + rg * 8 + hi * 4;
      unsigned w0 = cvtpk(o[dt][rg * 4 + 0], o[dt][rg * 4 + 1]);
      unsigned w1 = cvtpk(o[dt][rg * 4 + 2], o[dt][rg * 4 + 3]);
      int lin = qb * 256 + d0 * 2;
      int phys = lin ^ ((qb & 7) << 4);
      *reinterpret_cast<uint2*>(lds + phys) = make_uint2(w0, w1);
    }
  }
  __syncthreads();
  const int qr = tid >> 4, c16 = tid & 15;
#pragma unroll
  for (int it = 0; it < 8; ++it) {
    int q = qr + it * 16;
    int phys = (q * 256 + c16 * 16) ^ ((q & 7) << 4);
    s16x8 v = *reinterpret_cast<const s16x8*>(lds + phys);
    *reinterpret_cast<s16x8*>(Ao + ((size_t)(b * 2048 + qbk * 128 + q)) * 2048 + h * 128 + c16 * 8) = v;
  }
}

extern "C" void kernel_launch(void* const* d_in, const int* in_sizes, int n_in,
                              void* d_out, int out_size, void* d_ws, size_t ws_size,
                              hipStream_t stream) {
  const float* x      = (const float*)d_in[0];
  const float* past_k = (const float*)d_in[1];
  const float* past_v = (const float*)d_in[2];
  const float* Wq = (const float*)d_in[3];
  const float* bq = (const float*)d_in[4];
  const float* Wk = (const float*)d_in[5];
  const float* bk = (const float*)d_in[6];
  const float* Wv = (const float*)d_in[7];
  const float* bv = (const float*)d_in[8];
  const float* Wo = (const float*)d_in[9];
  const float* bo = (const float*)d_in[10];
  float* out = (float*)d_out;

  char* ws = (char*)d_ws;
  u16* xb   = (u16*)(ws);                    // x bf16 [4096,2048]; reused as ao after qkv
  u16* wqb  = (u16*)(ws + 16777216);
  u16* wkb  = (u16*)(ws + 25165824);
  u16* wvb  = (u16*)(ws + 33554432);
  u16* wob  = (u16*)(ws + 41943040);
  u16* kc   = (u16*)(ws + 50331648);         // K cache [B,H,4096,128]
  u16* qbuf = (u16*)(ws + 83886080);         // Q [B,H,2048,128]
  u16* vn   = (u16*)(ws + 100663296);        // V new [B,H,2048,128]
  u16* vt   = (u16*)(ws + 117440512);        // V^T [B,H,128,4096] row-major
  u16* ao   = xb;

  cvt_all<<<2048, 256, 0, stream>>>(x, Wq, Wk, Wv, Wo, past_k, xb, wqb, wkb, wvb, wob, kc);
  transpose_past_v<<<dim3(32, 32), 256, 0, stream>>>(past_v, vt);
  qkv_gemm8<<<768, 512, 0, stream>>>(xb, wqb, wkb, wvb, bq, bk, bv, qbuf, kc, vn);
  transpose_new_v<<<dim3(32, 32), 256, 0, stream>>>(vn, vt);
  attn_kernel<<<dim3(32, 16), 256, 0, stream>>>(qbuf, kc, vt, ao);
  proj_gemm<<<dim3(32, 16), 256, 0, stream>>>(ao, wob, bo, out);
}

// Round 11
// 383.854 us; speedup vs baseline: 1.1107x; 1.1107x over previous
//
#include <hip/hip_runtime.h>

typedef unsigned short u16;
typedef __attribute__((ext_vector_type(4))) float f32x4;
typedef __attribute__((ext_vector_type(16))) float f32x16;
typedef __attribute__((ext_vector_type(8))) short s16x8;
typedef __attribute__((ext_vector_type(2))) unsigned int u32x2v;

#define CEXP 0.12751742929f  // log2(e)/sqrt(128)

static __device__ __forceinline__ u16 f2bf(float x) {
  unsigned u = __float_as_uint(x);
  u = u + 0x7fffu + ((u >> 16) & 1u);
  return (u16)(u >> 16);
}
static __device__ __forceinline__ unsigned cvtpk(float a, float b) {
  unsigned r;
  asm("v_cvt_pk_bf16_f32 %0, %1, %2" : "=v"(r) : "v"(a), "v"(b));
  return r;
}
static __device__ __forceinline__ u32x2v pswap(unsigned a, unsigned b) {
  return __builtin_amdgcn_permlane32_swap(a, b, false, false);
}
static __device__ __forceinline__ f32x4 fzero() { f32x4 z; z[0]=0.f; z[1]=0.f; z[2]=0.f; z[3]=0.f; return z; }
static __device__ __forceinline__ f32x4 mfma16(s16x8 a, s16x8 b, f32x4 c) {
  return __builtin_amdgcn_mfma_f32_16x16x32_bf16(a, b, c, 0, 0, 0);
}
static __device__ __forceinline__ f32x16 mfma32(s16x8 a, s16x8 b, f32x16 c) {
  return __builtin_amdgcn_mfma_f32_32x32x16_bf16(a, b, c, 0, 0, 0);
}
static __device__ __forceinline__ void gld16(const void* g, void* l) {
  __builtin_amdgcn_global_load_lds((const __attribute__((address_space(1))) void*)g,
                                   (__attribute__((address_space(3))) void*)l, 16, 0, 0);
}

// ---------------- fused prep: blocks 0..1023 transpose past_v; blocks 1024.. do fp32->bf16 ----------------
__global__ void prep_fuse(const float* __restrict__ x, const float* __restrict__ wq,
                          const float* __restrict__ wk, const float* __restrict__ wv,
                          const float* __restrict__ wo, const float* __restrict__ pk,
                          const float* __restrict__ pv,
                          u16* __restrict__ xb, u16* __restrict__ wqb, u16* __restrict__ wkb,
                          u16* __restrict__ wvb, u16* __restrict__ wob, u16* __restrict__ kc,
                          u16* __restrict__ vt) {
  __shared__ u16 tile[64 * 138];
  const int bx = blockIdx.x, t = threadIdx.x;
  if (bx < 1024) {
    // transpose_past_v body: bh = bx>>5, pt = bx&31
    int bh = bx >> 5, pt = bx & 31;
    const float* s = pv + ((size_t)bh * 2048 + (size_t)pt * 64) * 128;
#pragma unroll
    for (int it = 0; it < 8; ++it) {
      int idx = it * 1024 + t * 4;
      int row = idx >> 7, col = idx & 127;
      float4 v = *reinterpret_cast<const float4*>(s + idx);
      u16* d = &tile[row * 138 + col];
      d[0] = f2bf(v.x); d[1] = f2bf(v.y); d[2] = f2bf(v.z); d[3] = f2bf(v.w);
    }
    __syncthreads();
    size_t dbase = (size_t)bh * 128 * 4096 + (size_t)pt * 64;
#pragma unroll
    for (int it = 0; it < 32; ++it) {
      int o = it * 256 + t;
      int dd = o >> 6, pos = o & 63;
      vt[dbase + (size_t)dd * 4096 + pos] = tile[pos * 138 + dd];
    }
    return;
  }
  // cvt body: grid-stride over 8388608 float4 groups
  int base = (bx - 1024) * 256 + t;
  int stride = 2048 * 256;
  for (int i4 = base; i4 < 8388608; i4 += stride) {
    const float* s; u16* d; int i; size_t di;
    if (i4 < 2097152)      { i = i4 * 4;             s = x;  d = xb;  di = i; }
    else if (i4 < 3145728) { i = (i4 - 2097152) * 4; s = wq; d = wqb; di = i; }
    else if (i4 < 4194304) { i = (i4 - 3145728) * 4; s = wk; d = wkb; di = i; }
    else if (i4 < 5242880) { i = (i4 - 4194304) * 4; s = wv; d = wvb; di = i; }
    else if (i4 < 6291456) { i = (i4 - 5242880) * 4; s = wo; d = wob; di = i; }
    else { i = (i4 - 6291456) * 4; s = pk; d = kc; di = (size_t)i + ((size_t)(i >> 18) << 18); }
    float4 v = *reinterpret_cast<const float4*>(s + i);
    ushort4 o;
    o.x = f2bf(v.x); o.y = f2bf(v.y); o.z = f2bf(v.z); o.w = f2bf(v.w);
    *reinterpret_cast<ushort4*>(d + di) = o;
  }
}

__global__ void transpose_new_v(const u16* __restrict__ src, u16* __restrict__ dst) {
  __shared__ u16 tile[64 * 138];
  int bh = blockIdx.y, pt = blockIdx.x;
  const u16* s = src + ((size_t)bh * 2048 + (size_t)pt * 64) * 128;
  int t = threadIdx.x;
#pragma unroll
  for (int it = 0; it < 8; ++it) {
    int idx = it * 1024 + t * 4;
    int row = idx >> 7, col = idx & 127;
    ushort4 v = *reinterpret_cast<const ushort4*>(s + idx);
    u16* d = &tile[row * 138 + col];
    d[0] = v.x; d[1] = v.y; d[2] = v.z; d[3] = v.w;
  }
  __syncthreads();
  size_t dbase = (size_t)bh * 128 * 4096 + 2048 + (size_t)pt * 64;
#pragma unroll
  for (int it = 0; it < 32; ++it) {
    int o = it * 256 + t;
    int dd = o >> 6, pos = o & 63;
    dst[dbase + (size_t)dd * 4096 + pos] = tile[pos * 138 + dd];
  }
}

// ---------------- 128x128 GEMM core, counted-vmcnt pipeline ----------------
static __device__ __forceinline__ void gemm_core(const u16* __restrict__ A, const u16* __restrict__ Wn,
                                                 int m0, char* ldsb, f32x4 (&acc)[4][4]) {
  const int tid = threadIdx.x;
  const int w = tid >> 6, lane = tid & 63, g = lane >> 4, ln = lane & 15;
#pragma unroll
  for (int mi = 0; mi < 4; ++mi)
#pragma unroll
    for (int ni = 0; ni < 4; ++ni) acc[mi][ni] = fzero();

  auto stage = [&](int buf, int k0) {
#pragma unroll
    for (int i = 0; i < 2; ++i) {
      int c = w * 2 + i;
      int p = c * 1024 + lane * 16;
      int row = p >> 6;
      int colb = (p & 63) ^ ((row & 3) << 4);
      const u16* sa = A + (size_t)(m0 + row) * 2048 + k0 + (colb >> 1);
      const u16* sw = Wn + (size_t)row * 2048 + k0 + (colb >> 1);
      char* da = ldsb + buf * 16384 + c * 1024;
      gld16(sa, da);
      gld16(sw, da + 8192);
    }
  };
  stage(0, 0);
  const int wr = w >> 1, wc = w & 1;
  for (int kt = 0; kt < 64; ++kt) {
    int cur = kt & 1;
    if (kt < 63) {
      stage(cur ^ 1, (kt + 1) * 32);
      asm volatile("s_waitcnt vmcnt(4)\n\ts_barrier" ::: "memory");  // tile kt landed; kt+1 in flight
    } else {
      asm volatile("s_waitcnt vmcnt(0)\n\ts_barrier" ::: "memory");
    }
    const char* bp = ldsb + cur * 16384;
    s16x8 af[4], bw[4];
#pragma unroll
    for (int mi = 0; mi < 4; ++mi) {
      int row = wr * 64 + mi * 16 + ln;
      int lin = row * 64 + g * 16;
      af[mi] = *reinterpret_cast<const s16x8*>(bp + (lin ^ ((row & 3) << 4)));
    }
#pragma unroll
    for (int ni = 0; ni < 4; ++ni) {
      int row = wc * 64 + ni * 16 + ln;
      int lin = row * 64 + g * 16;
      bw[ni] = *reinterpret_cast<const s16x8*>(bp + 8192 + (lin ^ ((row & 3) << 4)));
    }
#pragma unroll
    for (int mi = 0; mi < 4; ++mi)
#pragma unroll
      for (int ni = 0; ni < 4; ++ni)
        acc[mi][ni] = mfma16(af[mi], bw[ni], acc[mi][ni]);
    asm volatile("s_waitcnt lgkmcnt(0)\n\ts_barrier" ::: "memory");  // reads of cur done; no vm drain
  }
}

// ---------------- fused QKV projection ----------------
__global__ __launch_bounds__(256, 3) void qkv_gemm(const u16* __restrict__ xb,
    const u16* __restrict__ wq, const u16* __restrict__ wk, const u16* __restrict__ wv,
    const float* __restrict__ bq, const float* __restrict__ bk, const float* __restrict__ bv,
    u16* __restrict__ outq, u16* __restrict__ kc, u16* __restrict__ outv) {
  __shared__ char ldsb[32768];
  int m0 = blockIdx.x * 128;
  int ny = blockIdx.y;
  int wsel = ny >> 4, n0 = (ny & 15) * 128;
  const u16* W; const float* bias; u16* dst; int lrow, off;
  if (wsel == 0)      { W = wq; bias = bq; dst = outq; lrow = 2048; off = 0; }
  else if (wsel == 1) { W = wk; bias = bk; dst = kc;   lrow = 4096; off = 2048; }
  else                { W = wv; bias = bv; dst = outv; lrow = 2048; off = 0; }
  f32x4 acc[4][4];
  gemm_core(xb, W + (size_t)n0 * 2048, m0, ldsb, acc);
  const int tid = threadIdx.x, w = tid >> 6, lane = tid & 63, g = lane >> 4, ln = lane & 15;
  const int wr = w >> 1, wc = w & 1;
#pragma unroll
  for (int ni = 0; ni < 4; ++ni) {
    int j = n0 + wc * 64 + ni * 16 + ln;
    float bcol = bias[j];
    int h = j >> 7, hd = j & 127;
#pragma unroll
    for (int mi = 0; mi < 4; ++mi) {
#pragma unroll
      for (int r = 0; r < 4; ++r) {
        int rowg = m0 + wr * 64 + mi * 16 + g * 4 + r;
        int b = rowg >> 11, s = rowg & 2047;
        float val = acc[mi][ni][r] + bcol;
        dst[((size_t)(b * 16 + h) * lrow + off + s) * 128 + hd] = f2bf(val);
      }
    }
  }
}

// ---------------- output projection ----------------
__global__ __launch_bounds__(256, 3) void proj_gemm(const u16* __restrict__ ao, const u16* __restrict__ wo,
    const float* __restrict__ bo, float* __restrict__ out) {
  __shared__ char ldsb[32768];
  int m0 = blockIdx.x * 128, n0 = blockIdx.y * 128;
  f32x4 acc[4][4];
  gemm_core(ao, wo + (size_t)n0 * 2048, m0, ldsb, acc);
  const int tid = threadIdx.x, w = tid >> 6, lane = tid & 63, g = lane >> 4, ln = lane & 15;
  const int wr = w >> 1, wc = w & 1;
#pragma unroll
  for (int ni = 0; ni < 4; ++ni) {
    int j = n0 + wc * 64 + ni * 16 + ln;
    float bcol = bo[j];
#pragma unroll
    for (int mi = 0; mi < 4; ++mi) {
#pragma unroll
      for (int r = 0; r < 4; ++r) {
        int rowg = m0 + wr * 64 + mi * 16 + g * 4 + r;
        out[(size_t)rowg * 2048 + j] = acc[mi][ni][r] + bcol;
      }
    }
  }
}

// ---------------- flash attention (best measured: R6 config, 177 us) ----------------
// 32x32 MFMA, K+V LDS dbuf, vmcnt(8) counted pipeline, XOR-swizzle row-major tiles.
__global__ __launch_bounds__(256, 2) void attn_kernel(const u16* __restrict__ Qb,
    const u16* __restrict__ Kc, const u16* __restrict__ Vt, u16* __restrict__ Ao) {
  __shared__ char lds[65536];  // 2 bufs x (K 16KB + Vt 16KB)
  const int tid = threadIdx.x, w = tid >> 6, lane = tid & 63;
  const int hi = lane >> 5, l5 = lane & 31;
  const int bh = blockIdx.x;
  const int qy = blockIdx.y;
  const int qbk = (qy & 8) ? (15 - (qy & 7)) : qy;   // complementary pairing
  const int b = bh >> 4, h = bh & 15;
  const u16* Qbh = Qb + (size_t)bh * 2048 * 128;
  const u16* Kbh = Kc + (size_t)bh * 4096 * 128;
  const u16* Vbh = Vt + (size_t)bh * 128 * 4096;

  const int qrow0 = qbk * 128 + w * 32;
  const int qp = 2048 + qrow0 + l5;
  const int qpmin = 2048 + qrow0;
  const int ntiles = (2048 + qbk * 128 + 128) >> 6;

  s16x8 qf[8];
#pragma unroll
  for (int kc = 0; kc < 8; ++kc)
    qf[kc] = *reinterpret_cast<const s16x8*>(Qbh + (size_t)(qrow0 + l5) * 128 + kc * 16 + hi * 8);

  f32x16 o[4];
#pragma unroll
  for (int dt = 0; dt < 4; ++dt)
#pragma unroll
    for (int i = 0; i < 16; ++i) o[dt][i] = 0.f;
  float mrun = -3e38f, lrun = 0.f;

  auto stage = [&](int buf, int kv0) {
    char* base = lds + buf * 32768;
#pragma unroll
    for (int i = 0; i < 4; ++i) {
      int p = (w * 4 + i) * 1024 + lane * 16;
      int row = p >> 8;
      int colb = (p & 255) ^ ((row & 7) << 4);
      gld16(Kbh + (size_t)(kv0 + row) * 128 + (colb >> 1), base + (w * 4 + i) * 1024);
      int vrow = p >> 7;
      int vcol = (p & 127) ^ ((vrow & 7) << 4);
      gld16(Vbh + (size_t)vrow * 4096 + kv0 + (vcol >> 1), base + 16384 + (w * 4 + i) * 1024);
    }
  };

  stage(0, 0);
  for (int t = 0; t < ntiles; ++t) {
    const int kv0 = t * 64;
    const int cur = t & 1;
    if (t + 1 < ntiles) {
      stage(cur ^ 1, kv0 + 64);
      asm volatile("s_waitcnt vmcnt(8)\n\ts_barrier" ::: "memory");  // tile t landed; t+1 in flight
    } else {
      asm volatile("s_waitcnt vmcnt(0)\n\ts_barrier" ::: "memory");
    }
    const char* Kl = lds + cur * 32768;
    const char* Vl = Kl + 16384;
    if (kv0 <= qpmin + 31) {
      f32x16 s0, s1;
#pragma unroll
      for (int i = 0; i < 16; ++i) { s0[i] = 0.f; s1[i] = 0.f; }
      __builtin_amdgcn_s_setprio(1);
#pragma unroll
      for (int kc = 0; kc < 8; ++kc) {
        {
          int row = l5;
          int lin = row * 256 + kc * 32 + hi * 16;
          s16x8 a = *reinterpret_cast<const s16x8*>(Kl + (lin ^ ((row & 7) << 4)));
          s0 = mfma32(a, qf[kc], s0);
        }
        {
          int row = 32 + l5;
          int lin = row * 256 + kc * 32 + hi * 16;
          s16x8 a = *reinterpret_cast<const s16x8*>(Kl + (lin ^ ((row & 7) << 4)));
          s1 = mfma32(a, qf[kc], s1);
        }
      }
      __builtin_amdgcn_s_setprio(0);
      if (kv0 + 63 > qpmin) {
#pragma unroll
        for (int i = 0; i < 16; ++i) {
          int r0 = (i & 3) + 8 * (i >> 2) + 4 * hi;
          if (kv0 + r0 > qp) s0[i] = -3e38f;
          if (kv0 + 32 + r0 > qp) s1[i] = -3e38f;
        }
      }
      float pm = fmaxf(s0[0], s0[1]);
#pragma unroll
      for (int i = 2; i < 16; i += 2) pm = fmaxf(fmaxf(pm, s0[i]), s0[i + 1]);
#pragma unroll
      for (int i = 0; i < 16; i += 2) pm = fmaxf(fmaxf(pm, s1[i]), s1[i + 1]);
      {
        u32x2v rr = pswap(__float_as_uint(pm), __float_as_uint(pm));
        pm = fmaxf(pm, __uint_as_float(hi ? rr[0] : rr[1]));
      }
      float mnew = (pm > mrun + 8.f) ? pm : mrun;
      float fsc = exp2f((mrun - mnew) * CEXP);
      mrun = mnew;
      float r0 = 0.f, r1 = 0.f, r2 = 0.f, r3 = 0.f;
#pragma unroll
      for (int i = 0; i < 16; i += 4) {
        float p0 = exp2f((s0[i] - mnew) * CEXP);
        float p1 = exp2f((s0[i + 1] - mnew) * CEXP);
        float p2 = exp2f((s0[i + 2] - mnew) * CEXP);
        float p3 = exp2f((s0[i + 3] - mnew) * CEXP);
        s0[i] = p0; s0[i + 1] = p1; s0[i + 2] = p2; s0[i + 3] = p3;
        r0 += p0; r1 += p1; r2 += p2; r3 += p3;
      }
#pragma unroll
      for (int i = 0; i < 16; i += 4) {
        float p0 = exp2f((s1[i] - mnew) * CEXP);
        float p1 = exp2f((s1[i + 1] - mnew) * CEXP);
        float p2 = exp2f((s1[i + 2] - mnew) * CEXP);
        float p3 = exp2f((s1[i + 3] - mnew) * CEXP);
        s1[i] = p0; s1[i + 1] = p1; s1[i + 2] = p2; s1[i + 3] = p3;
        r0 += p0; r1 += p1; r2 += p2; r3 += p3;
      }
      float rs = (r0 + r1) + (r2 + r3);
      {
        u32x2v rr = pswap(__float_as_uint(rs), __float_as_uint(rs));
        rs += __uint_as_float(hi ? rr[0] : rr[1]);
      }
      lrun = lrun * fsc + rs;
      if (!__all(fsc == 1.f)) {
#pragma unroll
        for (int dt = 0; dt < 4; ++dt)
#pragma unroll
          for (int i = 0; i < 16; ++i) o[dt][i] *= fsc;
      }
      s16x8 pb[4];
#pragma unroll
      for (int c2 = 0; c2 < 4; ++c2) {
        const f32x16& sv = (c2 & 2) ? s1 : s0;
        const int b0 = (c2 & 1) * 8;
        unsigned x0 = cvtpk(sv[b0 + 0], sv[b0 + 1]);
        unsigned x1 = cvtpk(sv[b0 + 2], sv[b0 + 3]);
        unsigned y0 = cvtpk(sv[b0 + 4], sv[b0 + 5]);
        unsigned y1 = cvtpk(sv[b0 + 6], sv[b0 + 7]);
        u32x2v q0 = pswap(x0, y0);
        u32x2v q1 = pswap(x1, y1);
        union { unsigned u[4]; s16x8 v; } pu;
        pu.u[0] = q0[0]; pu.u[1] = q1[0]; pu.u[2] = q0[1]; pu.u[3] = q1[1];
        pb[c2] = pu.v;
      }
      __builtin_amdgcn_s_setprio(1);
#pragma unroll
      for (int dt = 0; dt < 4; ++dt) {
#pragma unroll
        for (int c2 = 0; c2 < 4; ++c2) {
          int row = dt * 32 + l5;
          int lin = row * 128 + c2 * 32 + hi * 16;
          s16x8 va = *reinterpret_cast<const s16x8*>(Vl + (lin ^ ((row & 7) << 4)));
          o[dt] = mfma32(va, pb[c2], o[dt]);
        }
      }
      __builtin_amdgcn_s_setprio(0);
    }
    asm volatile("s_waitcnt lgkmcnt(0)\n\ts_barrier" ::: "memory");
  }

  float li = 1.f / lrun;
#pragma unroll
  for (int dt = 0; dt < 4; ++dt)
#pragma unroll
    for (int i = 0; i < 16; ++i) o[dt][i] *= li;
  const int qb = w * 32 + l5;
#pragma unroll
  for (int dt = 0; dt < 4; ++dt) {
#pragma unroll
    for (int rg = 0; rg < 4; ++rg) {
      int d0 = dt * 32 + rg * 8 + hi * 4;
      unsigned w0 = cvtpk(o[dt][rg * 4 + 0], o[dt][rg * 4 + 1]);
      unsigned w1 = cvtpk(o[dt][rg * 4 + 2], o[dt][rg * 4 + 3]);
      int lin = qb * 256 + d0 * 2;
      int phys = lin ^ ((qb & 7) << 4);
      *reinterpret_cast<uint2*>(lds + phys) = make_uint2(w0, w1);
    }
  }
  __syncthreads();
  const int qr = tid >> 4, c16 = tid & 15;
#pragma unroll
  for (int it = 0; it < 8; ++it) {
    int q = qr + it * 16;
    int phys = (q * 256 + c16 * 16) ^ ((q & 7) << 4);
    s16x8 v = *reinterpret_cast<const s16x8*>(lds + phys);
    *reinterpret_cast<s16x8*>(Ao + ((size_t)(b * 2048 + qbk * 128 + q)) * 2048 + h * 128 + c16 * 8) = v;
  }
}

extern "C" void kernel_launch(void* const* d_in, const int* in_sizes, int n_in,
                              void* d_out, int out_size, void* d_ws, size_t ws_size,
                              hipStream_t stream) {
  const float* x      = (const float*)d_in[0];
  const float* past_k = (const float*)d_in[1];
  const float* past_v = (const float*)d_in[2];
  const float* Wq = (const float*)d_in[3];
  const float* bq = (const float*)d_in[4];
  const float* Wk = (const float*)d_in[5];
  const float* bk = (const float*)d_in[6];
  const float* Wv = (const float*)d_in[7];
  const float* bv = (const float*)d_in[8];
  const float* Wo = (const float*)d_in[9];
  const float* bo = (const float*)d_in[10];
  float* out = (float*)d_out;

  char* ws = (char*)d_ws;
  u16* xb   = (u16*)(ws);                    // x bf16 [4096,2048]; reused as ao after qkv
  u16* wqb  = (u16*)(ws + 16777216);
  u16* wkb  = (u16*)(ws + 25165824);
  u16* wvb  = (u16*)(ws + 33554432);
  u16* wob  = (u16*)(ws + 41943040);
  u16* kc   = (u16*)(ws + 50331648);         // K cache [B,H,4096,128]
  u16* qbuf = (u16*)(ws + 83886080);         // Q [B,H,2048,128]
  u16* vn   = (u16*)(ws + 100663296);        // V new [B,H,2048,128]
  u16* vt   = (u16*)(ws + 117440512);        // V^T [B,H,128,4096] row-major
  u16* ao   = xb;

  prep_fuse<<<3072, 256, 0, stream>>>(x, Wq, Wk, Wv, Wo, past_k, past_v,
                                      xb, wqb, wkb, wvb, wob, kc, vt);
  qkv_gemm<<<dim3(32, 48), 256, 0, stream>>>(xb, wqb, wkb, wvb, bq, bk, bv, qbuf, kc, vn);
  transpose_new_v<<<dim3(32, 32), 256, 0, stream>>>(vn, vt);
  attn_kernel<<<dim3(32, 16), 256, 0, stream>>>(qbuf, kc, vt, ao);
  proj_gemm<<<dim3(32, 16), 256, 0, stream>>>(ao, wob, bo, out);
}

// Round 12
// 372.792 us; speedup vs baseline: 1.1437x; 1.0297x over previous
//
#include <hip/hip_runtime.h>

typedef unsigned short u16;
typedef __attribute__((ext_vector_type(4))) float f32x4;
typedef __attribute__((ext_vector_type(16))) float f32x16;
typedef __attribute__((ext_vector_type(8))) short s16x8;
typedef __attribute__((ext_vector_type(2))) unsigned int u32x2v;

#define CEXP 0.12751742929f  // log2(e)/sqrt(128)

static __device__ __forceinline__ u16 f2bf(float x) {
  unsigned u = __float_as_uint(x);
  u = u + 0x7fffu + ((u >> 16) & 1u);
  return (u16)(u >> 16);
}
static __device__ __forceinline__ unsigned cvtpk(float a, float b) {
  unsigned r;
  asm("v_cvt_pk_bf16_f32 %0, %1, %2" : "=v"(r) : "v"(a), "v"(b));
  return r;
}
static __device__ __forceinline__ u32x2v pswap(unsigned a, unsigned b) {
  return __builtin_amdgcn_permlane32_swap(a, b, false, false);
}
static __device__ __forceinline__ f32x4 fzero() { f32x4 z; z[0]=0.f; z[1]=0.f; z[2]=0.f; z[3]=0.f; return z; }
static __device__ __forceinline__ f32x4 mfma16(s16x8 a, s16x8 b, f32x4 c) {
  return __builtin_amdgcn_mfma_f32_16x16x32_bf16(a, b, c, 0, 0, 0);
}
static __device__ __forceinline__ f32x16 mfma32(s16x8 a, s16x8 b, f32x16 c) {
  return __builtin_amdgcn_mfma_f32_32x32x16_bf16(a, b, c, 0, 0, 0);
}
static __device__ __forceinline__ void gld16(const void* g, void* l) {
  __builtin_amdgcn_global_load_lds((const __attribute__((address_space(1))) void*)g,
                                   (__attribute__((address_space(3))) void*)l, 16, 0, 0);
}

// ---------------- fused fp32 -> bf16 conversions (x, 4 weights, past_k) — no LDS, full occupancy ----------------
__global__ void cvt_all(const float* __restrict__ x, const float* __restrict__ wq,
                        const float* __restrict__ wk, const float* __restrict__ wv,
                        const float* __restrict__ wo, const float* __restrict__ pk,
                        u16* __restrict__ xb, u16* __restrict__ wqb, u16* __restrict__ wkb,
                        u16* __restrict__ wvb, u16* __restrict__ wob, u16* __restrict__ kc) {
  int stride = gridDim.x * blockDim.x;
  for (int i4 = blockIdx.x * blockDim.x + threadIdx.x; i4 < 8388608; i4 += stride) {
    const float* s; u16* d; int i; size_t di;
    if (i4 < 2097152)      { i = i4 * 4;             s = x;  d = xb;  di = i; }
    else if (i4 < 3145728) { i = (i4 - 2097152) * 4; s = wq; d = wqb; di = i; }
    else if (i4 < 4194304) { i = (i4 - 3145728) * 4; s = wk; d = wkb; di = i; }
    else if (i4 < 5242880) { i = (i4 - 4194304) * 4; s = wv; d = wvb; di = i; }
    else if (i4 < 6291456) { i = (i4 - 5242880) * 4; s = wo; d = wob; di = i; }
    else { i = (i4 - 6291456) * 4; s = pk; d = kc; di = (size_t)i + ((size_t)(i >> 18) << 18); }
    float4 v = *reinterpret_cast<const float4*>(s + i);
    ushort4 o;
    o.x = f2bf(v.x); o.y = f2bf(v.y); o.z = f2bf(v.z); o.w = f2bf(v.w);
    *reinterpret_cast<ushort4*>(d + di) = o;
  }
}

// ---------------- V transpose: [bh][2048][128] -> Vt [bh][128][4096] (row-major) ----------------
__global__ void transpose_past_v(const float* __restrict__ src, u16* __restrict__ dst) {
  __shared__ u16 tile[64 * 138];
  int bh = blockIdx.y, pt = blockIdx.x;
  const float* s = src + ((size_t)bh * 2048 + (size_t)pt * 64) * 128;
  int t = threadIdx.x;
#pragma unroll
  for (int it = 0; it < 8; ++it) {
    int idx = it * 1024 + t * 4;
    int row = idx >> 7, col = idx & 127;
    float4 v = *reinterpret_cast<const float4*>(s + idx);
    u16* d = &tile[row * 138 + col];
    d[0] = f2bf(v.x); d[1] = f2bf(v.y); d[2] = f2bf(v.z); d[3] = f2bf(v.w);
  }
  __syncthreads();
  size_t dbase = (size_t)bh * 128 * 4096 + (size_t)pt * 64;
#pragma unroll
  for (int it = 0; it < 32; ++it) {
    int o = it * 256 + t;
    int dd = o >> 6, pos = o & 63;
    dst[dbase + (size_t)dd * 4096 + pos] = tile[pos * 138 + dd];
  }
}

__global__ void transpose_new_v(const u16* __restrict__ src, u16* __restrict__ dst) {
  __shared__ u16 tile[64 * 138];
  int bh = blockIdx.y, pt = blockIdx.x;
  const u16* s = src + ((size_t)bh * 2048 + (size_t)pt * 64) * 128;
  int t = threadIdx.x;
#pragma unroll
  for (int it = 0; it < 8; ++it) {
    int idx = it * 1024 + t * 4;
    int row = idx >> 7, col = idx & 127;
    ushort4 v = *reinterpret_cast<const ushort4*>(s + idx);
    u16* d = &tile[row * 138 + col];
    d[0] = v.x; d[1] = v.y; d[2] = v.z; d[3] = v.w;
  }
  __syncthreads();
  size_t dbase = (size_t)bh * 128 * 4096 + 2048 + (size_t)pt * 64;
#pragma unroll
  for (int it = 0; it < 32; ++it) {
    int o = it * 256 + t;
    int dd = o >> 6, pos = o & 63;
    dst[dbase + (size_t)dd * 4096 + pos] = tile[pos * 138 + dd];
  }
}

// ---------------- 128x128 GEMM core, counted-vmcnt pipeline ----------------
static __device__ __forceinline__ void gemm_core(const u16* __restrict__ A, const u16* __restrict__ Wn,
                                                 int m0, char* ldsb, f32x4 (&acc)[4][4]) {
  const int tid = threadIdx.x;
  const int w = tid >> 6, lane = tid & 63, g = lane >> 4, ln = lane & 15;
#pragma unroll
  for (int mi = 0; mi < 4; ++mi)
#pragma unroll
    for (int ni = 0; ni < 4; ++ni) acc[mi][ni] = fzero();

  auto stage = [&](int buf, int k0) {
#pragma unroll
    for (int i = 0; i < 2; ++i) {
      int c = w * 2 + i;
      int p = c * 1024 + lane * 16;
      int row = p >> 6;
      int colb = (p & 63) ^ ((row & 3) << 4);
      const u16* sa = A + (size_t)(m0 + row) * 2048 + k0 + (colb >> 1);
      const u16* sw = Wn + (size_t)row * 2048 + k0 + (colb >> 1);
      char* da = ldsb + buf * 16384 + c * 1024;
      gld16(sa, da);
      gld16(sw, da + 8192);
    }
  };
  stage(0, 0);
  const int wr = w >> 1, wc = w & 1;
  for (int kt = 0; kt < 64; ++kt) {
    int cur = kt & 1;
    if (kt < 63) {
      stage(cur ^ 1, (kt + 1) * 32);
      asm volatile("s_waitcnt vmcnt(4)\n\ts_barrier" ::: "memory");  // tile kt landed; kt+1 in flight
    } else {
      asm volatile("s_waitcnt vmcnt(0)\n\ts_barrier" ::: "memory");
    }
    const char* bp = ldsb + cur * 16384;
    s16x8 af[4], bw[4];
#pragma unroll
    for (int mi = 0; mi < 4; ++mi) {
      int row = wr * 64 + mi * 16 + ln;
      int lin = row * 64 + g * 16;
      af[mi] = *reinterpret_cast<const s16x8*>(bp + (lin ^ ((row & 3) << 4)));
    }
#pragma unroll
    for (int ni = 0; ni < 4; ++ni) {
      int row = wc * 64 + ni * 16 + ln;
      int lin = row * 64 + g * 16;
      bw[ni] = *reinterpret_cast<const s16x8*>(bp + 8192 + (lin ^ ((row & 3) << 4)));
    }
#pragma unroll
    for (int mi = 0; mi < 4; ++mi)
#pragma unroll
      for (int ni = 0; ni < 4; ++ni)
        acc[mi][ni] = mfma16(af[mi], bw[ni], acc[mi][ni]);
    asm volatile("s_waitcnt lgkmcnt(0)\n\ts_barrier" ::: "memory");  // reads of cur done; no vm drain
  }
}

// ---------------- fused QKV projection ----------------
__global__ __launch_bounds__(256, 3) void qkv_gemm(const u16* __restrict__ xb,
    const u16* __restrict__ wq, const u16* __restrict__ wk, const u16* __restrict__ wv,
    const float* __restrict__ bq, const float* __restrict__ bk, const float* __restrict__ bv,
    u16* __restrict__ outq, u16* __restrict__ kc, u16* __restrict__ outv) {
  __shared__ char ldsb[32768];
  int m0 = blockIdx.x * 128;
  int ny = blockIdx.y;
  int wsel = ny >> 4, n0 = (ny & 15) * 128;
  const u16* W; const float* bias; u16* dst; int lrow, off;
  if (wsel == 0)      { W = wq; bias = bq; dst = outq; lrow = 2048; off = 0; }
  else if (wsel == 1) { W = wk; bias = bk; dst = kc;   lrow = 4096; off = 2048; }
  else                { W = wv; bias = bv; dst = outv; lrow = 2048; off = 0; }
  f32x4 acc[4][4];
  gemm_core(xb, W + (size_t)n0 * 2048, m0, ldsb, acc);
  const int tid = threadIdx.x, w = tid >> 6, lane = tid & 63, g = lane >> 4, ln = lane & 15;
  const int wr = w >> 1, wc = w & 1;
#pragma unroll
  for (int ni = 0; ni < 4; ++ni) {
    int j = n0 + wc * 64 + ni * 16 + ln;
    float bcol = bias[j];
    int h = j >> 7, hd = j & 127;
#pragma unroll
    for (int mi = 0; mi < 4; ++mi) {
#pragma unroll
      for (int r = 0; r < 4; ++r) {
        int rowg = m0 + wr * 64 + mi * 16 + g * 4 + r;
        int b = rowg >> 11, s = rowg & 2047;
        float val = acc[mi][ni][r] + bcol;
        dst[((size_t)(b * 16 + h) * lrow + off + s) * 128 + hd] = f2bf(val);
      }
    }
  }
}

// ---------------- output projection ----------------
__global__ __launch_bounds__(256, 3) void proj_gemm(const u16* __restrict__ ao, const u16* __restrict__ wo,
    const float* __restrict__ bo, float* __restrict__ out) {
  __shared__ char ldsb[32768];
  int m0 = blockIdx.x * 128, n0 = blockIdx.y * 128;
  f32x4 acc[4][4];
  gemm_core(ao, wo + (size_t)n0 * 2048, m0, ldsb, acc);
  const int tid = threadIdx.x, w = tid >> 6, lane = tid & 63, g = lane >> 4, ln = lane & 15;
  const int wr = w >> 1, wc = w & 1;
#pragma unroll
  for (int ni = 0; ni < 4; ++ni) {
    int j = n0 + wc * 64 + ni * 16 + ln;
    float bcol = bo[j];
#pragma unroll
    for (int mi = 0; mi < 4; ++mi) {
#pragma unroll
      for (int r = 0; r < 4; ++r) {
        int rowg = m0 + wr * 64 + mi * 16 + g * 4 + r;
        out[(size_t)rowg * 2048 + j] = acc[mi][ni][r] + bcol;
      }
    }
  }
}

// ---------------- flash attention (best measured config: 177 us, reproduced 4x) ----------------
// 32x32 MFMA, K+V LDS dbuf, vmcnt(8) counted pipeline, XOR-swizzle row-major tiles.
__global__ __launch_bounds__(256, 2) void attn_kernel(const u16* __restrict__ Qb,
    const u16* __restrict__ Kc, const u16* __restrict__ Vt, u16* __restrict__ Ao) {
  __shared__ char lds[65536];  // 2 bufs x (K 16KB + Vt 16KB)
  const int tid = threadIdx.x, w = tid >> 6, lane = tid & 63;
  const int hi = lane >> 5, l5 = lane & 31;
  const int bh = blockIdx.x;
  const int qy = blockIdx.y;
  const int qbk = (qy & 8) ? (15 - (qy & 7)) : qy;   // complementary pairing
  const int b = bh >> 4, h = bh & 15;
  const u16* Qbh = Qb + (size_t)bh * 2048 * 128;
  const u16* Kbh = Kc + (size_t)bh * 4096 * 128;
  const u16* Vbh = Vt + (size_t)bh * 128 * 4096;

  const int qrow0 = qbk * 128 + w * 32;
  const int qp = 2048 + qrow0 + l5;
  const int qpmin = 2048 + qrow0;
  const int ntiles = (2048 + qbk * 128 + 128) >> 6;

  s16x8 qf[8];
#pragma unroll
  for (int kc = 0; kc < 8; ++kc)
    qf[kc] = *reinterpret_cast<const s16x8*>(Qbh + (size_t)(qrow0 + l5) * 128 + kc * 16 + hi * 8);

  f32x16 o[4];
#pragma unroll
  for (int dt = 0; dt < 4; ++dt)
#pragma unroll
    for (int i = 0; i < 16; ++i) o[dt][i] = 0.f;
  float mrun = -3e38f, lrun = 0.f;

  auto stage = [&](int buf, int kv0) {
    char* base = lds + buf * 32768;
#pragma unroll
    for (int i = 0; i < 4; ++i) {
      int p = (w * 4 + i) * 1024 + lane * 16;
      int row = p >> 8;
      int colb = (p & 255) ^ ((row & 7) << 4);
      gld16(Kbh + (size_t)(kv0 + row) * 128 + (colb >> 1), base + (w * 4 + i) * 1024);
      int vrow = p >> 7;
      int vcol = (p & 127) ^ ((vrow & 7) << 4);
      gld16(Vbh + (size_t)vrow * 4096 + kv0 + (vcol >> 1), base + 16384 + (w * 4 + i) * 1024);
    }
  };

  stage(0, 0);
  for (int t = 0; t < ntiles; ++t) {
    const int kv0 = t * 64;
    const int cur = t & 1;
    if (t + 1 < ntiles) {
      stage(cur ^ 1, kv0 + 64);
      asm volatile("s_waitcnt vmcnt(8)\n\ts_barrier" ::: "memory");  // tile t landed; t+1 in flight
    } else {
      asm volatile("s_waitcnt vmcnt(0)\n\ts_barrier" ::: "memory");
    }
    const char* Kl = lds + cur * 32768;
    const char* Vl = Kl + 16384;
    if (kv0 <= qpmin + 31) {
      f32x16 s0, s1;
#pragma unroll
      for (int i = 0; i < 16; ++i) { s0[i] = 0.f; s1[i] = 0.f; }
      __builtin_amdgcn_s_setprio(1);
#pragma unroll
      for (int kc = 0; kc < 8; ++kc) {
        {
          int row = l5;
          int lin = row * 256 + kc * 32 + hi * 16;
          s16x8 a = *reinterpret_cast<const s16x8*>(Kl + (lin ^ ((row & 7) << 4)));
          s0 = mfma32(a, qf[kc], s0);
        }
        {
          int row = 32 + l5;
          int lin = row * 256 + kc * 32 + hi * 16;
          s16x8 a = *reinterpret_cast<const s16x8*>(Kl + (lin ^ ((row & 7) << 4)));
          s1 = mfma32(a, qf[kc], s1);
        }
      }
      __builtin_amdgcn_s_setprio(0);
      if (kv0 + 63 > qpmin) {
#pragma unroll
        for (int i = 0; i < 16; ++i) {
          int r0 = (i & 3) + 8 * (i >> 2) + 4 * hi;
          if (kv0 + r0 > qp) s0[i] = -3e38f;
          if (kv0 + 32 + r0 > qp) s1[i] = -3e38f;
        }
      }
      float pm = fmaxf(s0[0], s0[1]);
#pragma unroll
      for (int i = 2; i < 16; i += 2) pm = fmaxf(fmaxf(pm, s0[i]), s0[i + 1]);
#pragma unroll
      for (int i = 0; i < 16; i += 2) pm = fmaxf(fmaxf(pm, s1[i]), s1[i + 1]);
      {
        u32x2v rr = pswap(__float_as_uint(pm), __float_as_uint(pm));
        pm = fmaxf(pm, __uint_as_float(hi ? rr[0] : rr[1]));
      }
      float mnew = (pm > mrun + 8.f) ? pm : mrun;
      float fsc = exp2f((mrun - mnew) * CEXP);
      mrun = mnew;
      float r0 = 0.f, r1 = 0.f, r2 = 0.f, r3 = 0.f;
#pragma unroll
      for (int i = 0; i < 16; i += 4) {
        float p0 = exp2f((s0[i] - mnew) * CEXP);
        float p1 = exp2f((s0[i + 1] - mnew) * CEXP);
        float p2 = exp2f((s0[i + 2] - mnew) * CEXP);
        float p3 = exp2f((s0[i + 3] - mnew) * CEXP);
        s0[i] = p0; s0[i + 1] = p1; s0[i + 2] = p2; s0[i + 3] = p3;
        r0 += p0; r1 += p1; r2 += p2; r3 += p3;
      }
#pragma unroll
      for (int i = 0; i < 16; i += 4) {
        float p0 = exp2f((s1[i] - mnew) * CEXP);
        float p1 = exp2f((s1[i + 1] - mnew) * CEXP);
        float p2 = exp2f((s1[i + 2] - mnew) * CEXP);
        float p3 = exp2f((s1[i + 3] - mnew) * CEXP);
        s1[i] = p0; s1[i + 1] = p1; s1[i + 2] = p2; s1[i + 3] = p3;
        r0 += p0; r1 += p1; r2 += p2; r3 += p3;
      }
      float rs = (r0 + r1) + (r2 + r3);
      {
        u32x2v rr = pswap(__float_as_uint(rs), __float_as_uint(rs));
        rs += __uint_as_float(hi ? rr[0] : rr[1]);
      }
      lrun = lrun * fsc + rs;
      if (!__all(fsc == 1.f)) {
#pragma unroll
        for (int dt = 0; dt < 4; ++dt)
#pragma unroll
          for (int i = 0; i < 16; ++i) o[dt][i] *= fsc;
      }
      s16x8 pb[4];
#pragma unroll
      for (int c2 = 0; c2 < 4; ++c2) {
        const f32x16& sv = (c2 & 2) ? s1 : s0;
        const int b0 = (c2 & 1) * 8;
        unsigned x0 = cvtpk(sv[b0 + 0], sv[b0 + 1]);
        unsigned x1 = cvtpk(sv[b0 + 2], sv[b0 + 3]);
        unsigned y0 = cvtpk(sv[b0 + 4], sv[b0 + 5]);
        unsigned y1 = cvtpk(sv[b0 + 6], sv[b0 + 7]);
        u32x2v q0 = pswap(x0, y0);
        u32x2v q1 = pswap(x1, y1);
        union { unsigned u[4]; s16x8 v; } pu;
        pu.u[0] = q0[0]; pu.u[1] = q1[0]; pu.u[2] = q0[1]; pu.u[3] = q1[1];
        pb[c2] = pu.v;
      }
      __builtin_amdgcn_s_setprio(1);
#pragma unroll
      for (int dt = 0; dt < 4; ++dt) {
#pragma unroll
        for (int c2 = 0; c2 < 4; ++c2) {
          int row = dt * 32 + l5;
          int lin = row * 128 + c2 * 32 + hi * 16;
          s16x8 va = *reinterpret_cast<const s16x8*>(Vl + (lin ^ ((row & 7) << 4)));
          o[dt] = mfma32(va, pb[c2], o[dt]);
        }
      }
      __builtin_amdgcn_s_setprio(0);
    }
    asm volatile("s_waitcnt lgkmcnt(0)\n\ts_barrier" ::: "memory");
  }

  float li = 1.f / lrun;
#pragma unroll
  for (int dt = 0; dt < 4; ++dt)
#pragma unroll
    for (int i = 0; i < 16; ++i) o[dt][i] *= li;
  const int qb = w * 32 + l5;
#pragma unroll
  for (int dt = 0; dt < 4; ++dt) {
#pragma unroll
    for (int rg = 0; rg < 4; ++rg) {
      int d0 = dt * 32 + rg * 8 + hi * 4;
      unsigned w0 = cvtpk(o[dt][rg * 4 + 0], o[dt][rg * 4 + 1]);
      unsigned w1 = cvtpk(o[dt][rg * 4 + 2], o[dt][rg * 4 + 3]);
      int lin = qb * 256 + d0 * 2;
      int phys = lin ^ ((qb & 7) << 4);
      *reinterpret_cast<uint2*>(lds + phys) = make_uint2(w0, w1);
    }
  }
  __syncthreads();
  const int qr = tid >> 4, c16 = tid & 15;
#pragma unroll
  for (int it = 0; it < 8; ++it) {
    int q = qr + it * 16;
    int phys = (q * 256 + c16 * 16) ^ ((q & 7) << 4);
    s16x8 v = *reinterpret_cast<const s16x8*>(lds + phys);
    *reinterpret_cast<s16x8*>(Ao + ((size_t)(b * 2048 + qbk * 128 + q)) * 2048 + h * 128 + c16 * 8) = v;
  }
}

extern "C" void kernel_launch(void* const* d_in, const int* in_sizes, int n_in,
                              void* d_out, int out_size, void* d_ws, size_t ws_size,
                              hipStream_t stream) {
  const float* x      = (const float*)d_in[0];
  const float* past_k = (const float*)d_in[1];
  const float* past_v = (const float*)d_in[2];
  const float* Wq = (const float*)d_in[3];
  const float* bq = (const float*)d_in[4];
  const float* Wk = (const float*)d_in[5];
  const float* bk = (const float*)d_in[6];
  const float* Wv = (const float*)d_in[7];
  const float* bv = (const float*)d_in[8];
  const float* Wo = (const float*)d_in[9];
  const float* bo = (const float*)d_in[10];
  float* out = (float*)d_out;

  char* ws = (char*)d_ws;
  u16* xb   = (u16*)(ws);                    // x bf16 [4096,2048]; reused as ao after qkv
  u16* wqb  = (u16*)(ws + 16777216);
  u16* wkb  = (u16*)(ws + 25165824);
  u16* wvb  = (u16*)(ws + 33554432);
  u16* wob  = (u16*)(ws + 41943040);
  u16* kc   = (u16*)(ws + 50331648);         // K cache [B,H,4096,128]
  u16* qbuf = (u16*)(ws + 83886080);         // Q [B,H,2048,128]
  u16* vn   = (u16*)(ws + 100663296);        // V new [B,H,2048,128]
  u16* vt   = (u16*)(ws + 117440512);        // V^T [B,H,128,4096] row-major
  u16* ao   = xb;

  cvt_all<<<2048, 256, 0, stream>>>(x, Wq, Wk, Wv, Wo, past_k, xb, wqb, wkb, wvb, wob, kc);
  transpose_past_v<<<dim3(32, 32), 256, 0, stream>>>(past_v, vt);
  qkv_gemm<<<dim3(32, 48), 256, 0, stream>>>(xb, wqb, wkb, wvb, bq, bk, bv, qbuf, kc, vn);
  transpose_new_v<<<dim3(32, 32), 256, 0, stream>>>(vn, vt);
  attn_kernel<<<dim3(32, 16), 256, 0, stream>>>(qbuf, kc, vt, ao);
  proj_gemm<<<dim3(32, 16), 256, 0, stream>>>(ao, wob, bo, out);
}